// Round 1
// baseline (863.526 us; speedup 1.0000x reference)
//
#include <hip/hip_runtime.h>
#include <math.h>

#define BATCH 256
#define CIN   512
#define CP    256
#define HW    361
#define NOUT  6

typedef short bf16x8 __attribute__((ext_vector_type(8)));
typedef float f32x4  __attribute__((ext_vector_type(4)));

__device__ __forceinline__ short f2bf(float f) {
    unsigned u = __float_as_uint(f);
    u += 0x7fffu + ((u >> 16) & 1u);
    return (short)(u >> 16);
}

__device__ __forceinline__ float mish_f(float v) {
    float sp = (v > 20.f) ? v : log1pf(expf(v));
    return v * tanhf(sp);
}

// ---------------------------------------------------------------------------
// K1: fused conv1p + conv1g GEMM (bf16 MFMA), per-batch GEMM 512x361x512.
// Grid: x = hw-tile (3 of 128), y = o-tile (4 of 128; 0-1 = p, 2-3 = g), z = b.
// p-tiles: write outp_pre f32. g-tiles: beta+mask+mish, block-level sum/max
// partials per channel (3 hw-tiles -> psum/pmax[b][c][3]).
// ---------------------------------------------------------------------------
__global__ __launch_bounds__(256) void k1_conv1(
    const float* __restrict__ x, const float* __restrict__ mask,
    const float* __restrict__ w1p, const float* __restrict__ w1g,
    const float* __restrict__ beta_g,
    float* __restrict__ outp_pre, float* __restrict__ psum, float* __restrict__ pmax)
{
    const int n = blockIdx.x, m = blockIdx.y, b = blockIdx.z;
    const int tid = threadIdx.x;
    const int lane = tid & 63, wid = tid >> 6;
    const int wm = wid >> 1, wn = wid & 1;
    const int lc = lane & 15, lg = lane >> 4;
    const int hw0 = n * 128;

    __shared__ short As[128 * 40];   // weights tile [row][k], pad 40
    __shared__ short Bs[128 * 40];   // x tile transposed [hw][k], pad 40
    __shared__ float maskS[128];
    __shared__ float betaS[128];
    __shared__ float redS[128 * 2];
    __shared__ float redM[128 * 2];

    const float* wsrc = (m < 2) ? w1p : w1g;
    const int wrow0 = (m & 1) * 128;

    if (tid < 128) {
        int hwg = hw0 + tid;
        maskS[tid] = (hwg < HW) ? mask[b * HW + hwg] : 0.f;
        betaS[tid] = (m >= 2) ? beta_g[(m - 2) * 128 + tid] : 0.f;
    }

    f32x4 acc[4][4];
    #pragma unroll
    for (int i = 0; i < 4; ++i)
        #pragma unroll
        for (int j = 0; j < 4; ++j)
            acc[i][j] = (f32x4){0.f, 0.f, 0.f, 0.f};

    const int srow = tid & 127;   // staging row (A: o-row, B: hw)
    const int skh  = tid >> 7;    // staging k-half (0/1), 16 elems each

    for (int kb = 0; kb < CIN / 32; ++kb) {
        const int c0 = kb * 32;
        // ---- stage A (weights): row-contiguous 16 floats per thread
        {
            const float* src = wsrc + (size_t)(wrow0 + srow) * CIN + c0 + skh * 16;
            float f[16];
            *(float4*)(f)      = *(const float4*)(src);
            *(float4*)(f + 4)  = *(const float4*)(src + 4);
            *(float4*)(f + 8)  = *(const float4*)(src + 8);
            *(float4*)(f + 12) = *(const float4*)(src + 12);
            bf16x8 lo, hi;
            #pragma unroll
            for (int i = 0; i < 8; ++i) { lo[i] = f2bf(f[i]); hi[i] = f2bf(f[8 + i]); }
            *(bf16x8*)(&As[srow * 40 + skh * 16])     = lo;
            *(bf16x8*)(&As[srow * 40 + skh * 16 + 8]) = hi;
        }
        // ---- stage B (x): per-thread 16 c for one hw (coalesced across lanes)
        {
            int hwg = hw0 + srow;
            bool v = hwg < HW;
            const float* src = x + ((size_t)b * CIN + c0 + skh * 16) * HW + hwg;
            bf16x8 lo, hi;
            #pragma unroll
            for (int i = 0; i < 8; ++i) {
                float f0 = v ? src[(size_t)i * HW] : 0.f;
                float f1 = v ? src[(size_t)(i + 8) * HW] : 0.f;
                lo[i] = f2bf(f0); hi[i] = f2bf(f1);
            }
            *(bf16x8*)(&Bs[srow * 40 + skh * 16])     = lo;
            *(bf16x8*)(&Bs[srow * 40 + skh * 16 + 8]) = hi;
        }
        __syncthreads();

        bf16x8 aF[4], bF[4];
        #pragma unroll
        for (int mf = 0; mf < 4; ++mf)
            aF[mf] = *(const bf16x8*)(&As[(wm * 64 + mf * 16 + lc) * 40 + lg * 8]);
        #pragma unroll
        for (int nf = 0; nf < 4; ++nf)
            bF[nf] = *(const bf16x8*)(&Bs[(wn * 64 + nf * 16 + lc) * 40 + lg * 8]);
        #pragma unroll
        for (int mf = 0; mf < 4; ++mf)
            #pragma unroll
            for (int nf = 0; nf < 4; ++nf)
                acc[mf][nf] = __builtin_amdgcn_mfma_f32_16x16x32_bf16(
                    aF[mf], bF[nf], acc[mf][nf], 0, 0, 0);
        __syncthreads();
    }

    if (m < 2) {
        // p-branch: store pre-activation conv1p output
        #pragma unroll
        for (int mf = 0; mf < 4; ++mf) {
            int ch = m * 128 + wm * 64 + mf * 16 + lg * 4;
            #pragma unroll
            for (int nf = 0; nf < 4; ++nf) {
                int hw = hw0 + wn * 64 + nf * 16 + lc;
                if (hw < HW) {
                    #pragma unroll
                    for (int j = 0; j < 4; ++j)
                        outp_pre[((size_t)(b * CP + ch + j)) * HW + hw] = acc[mf][nf][j];
                }
            }
        }
    } else {
        // g-branch: mish((acc+beta)*mask); per-channel sum & max partials
        #pragma unroll
        for (int mf = 0; mf < 4; ++mf) {
            #pragma unroll
            for (int j = 0; j < 4; ++j) {
                int rloc = wm * 64 + mf * 16 + lg * 4 + j;
                float beta = betaS[rloc];
                float s = 0.f, mx = -INFINITY;
                #pragma unroll
                for (int nf = 0; nf < 4; ++nf) {
                    int cl = wn * 64 + nf * 16 + lc;
                    int hw = hw0 + cl;
                    float mv = maskS[cl];
                    float val = mish_f((acc[mf][nf][j] + beta) * mv);
                    if (hw < HW) {
                        s += val * mv;
                        mx = fmaxf(mx, val + mv - 1.f);
                    }
                }
                #pragma unroll
                for (int off = 1; off < 16; off <<= 1) {
                    s += __shfl_xor(s, off, 64);
                    mx = fmaxf(mx, __shfl_xor(mx, off, 64));
                }
                if (lc == 0) { redS[rloc * 2 + wn] = s; redM[rloc * 2 + wn] = mx; }
            }
        }
        __syncthreads();
        if (tid < 128) {
            int ch = (m - 2) * 128 + tid;
            float s = redS[tid * 2] + redS[tid * 2 + 1];
            float mx = fmaxf(redM[tid * 2], redM[tid * 2 + 1]);
            psum[((size_t)(b * CP + ch)) * 3 + n] = s;
            pmax[((size_t)(b * CP + ch)) * 3 + n] = mx;
        }
    }
}

// ---------------------------------------------------------------------------
// K2: per-batch pooled vector + linear_g. Grid 256 blocks x 256 threads.
// ---------------------------------------------------------------------------
__global__ __launch_bounds__(256) void k2_pool_linear(
    const float* __restrict__ mask, const float* __restrict__ psum,
    const float* __restrict__ pmax, const float* __restrict__ lw,
    float* __restrict__ g_out)
{
    int b = blockIdx.x, t = threadIdx.x;
    __shared__ float pooled[768];
    __shared__ float msr[4];

    float s = 0.f;
    for (int i = t; i < HW; i += 256) s += mask[b * HW + i];
    #pragma unroll
    for (int off = 1; off < 64; off <<= 1) s += __shfl_xor(s, off, 64);
    if ((t & 63) == 0) msr[t >> 6] = s;
    __syncthreads();
    float msum = msr[0] + msr[1] + msr[2] + msr[3];

    {
        int c = t;
        const float* ps = psum + (size_t)(b * CP + c) * 3;
        const float* pm = pmax + (size_t)(b * CP + c) * 3;
        float s3 = ps[0] + ps[1] + ps[2];
        float m3 = fmaxf(fmaxf(pm[0], pm[1]), pm[2]);
        float mean = s3 / msum;
        float sq = (sqrtf(msum) - 14.f) * 0.1f;
        pooled[c] = mean; pooled[256 + c] = mean * sq; pooled[512 + c] = m3;
    }
    __syncthreads();
    {
        int o = t;
        const float* wrow = lw + (size_t)o * 768;
        float acc = 0.f;
        #pragma unroll 4
        for (int j = 0; j < 768; ++j) acc += pooled[j] * wrow[j];
        g_out[b * CP + o] = acc;
    }
}

// ---------------------------------------------------------------------------
// K3: final fused mish((outp_pre+g+beta2)*mask) -> conv2p -> mask bias.
// Grid (6 hw-tiles, 256 b) x 256 threads (64 hw x 4 c-groups).
// ---------------------------------------------------------------------------
__global__ __launch_bounds__(256) void k3_final(
    const float* __restrict__ outp_pre, const float* __restrict__ mask,
    const float* __restrict__ g_out, const float* __restrict__ beta2,
    const float* __restrict__ w2, float* __restrict__ out)
{
    int ht = blockIdx.x, b = blockIdx.y;
    int t = threadIdx.x;
    __shared__ float w2S[NOUT * 256];
    __shared__ float gbS[256];
    __shared__ float part[NOUT][256];

    for (int i = t; i < NOUT * 256; i += 256) w2S[i] = w2[i];
    gbS[t] = g_out[b * CP + t] + beta2[t];
    __syncthreads();

    int hw = t & 63, cg = t >> 6;
    int hwg = ht * 64 + hw;
    bool valid = hwg < HW;
    float maskv = valid ? mask[b * HW + hwg] : 0.f;

    float acc[NOUT] = {0.f, 0.f, 0.f, 0.f, 0.f, 0.f};
    const float* src = outp_pre + ((size_t)(b * CP + cg * 64)) * HW + hwg;
    #pragma unroll 4
    for (int ci = 0; ci < 64; ++ci) {
        float v = valid ? src[(size_t)ci * HW] : 0.f;
        float mm = mish_f((v + gbS[cg * 64 + ci]) * maskv);
        #pragma unroll
        for (int o = 0; o < NOUT; ++o) acc[o] += mm * w2S[o * 256 + cg * 64 + ci];
    }
    #pragma unroll
    for (int o = 0; o < NOUT; ++o) part[o][t] = acc[o];
    __syncthreads();

    for (int idx = t; idx < NOUT * 64; idx += 256) {
        int o = idx >> 6, h2 = idx & 63;
        int hg = ht * 64 + h2;
        if (hg < HW) {
            float mv = mask[b * HW + hg];
            float sum = part[o][h2] + part[o][64 + h2] + part[o][128 + h2] + part[o][192 + h2];
            out[((size_t)(b * NOUT + o)) * HW + hg] = sum - (1.f - mv) * 5000.f;
        }
    }
}

extern "C" void kernel_launch(void* const* d_in, const int* in_sizes, int n_in,
                              void* d_out, int out_size, void* d_ws, size_t ws_size,
                              hipStream_t stream) {
    const float* x     = (const float*)d_in[0];
    const float* mask  = (const float*)d_in[1];
    const float* w1p   = (const float*)d_in[2];
    const float* w1g   = (const float*)d_in[3];
    const float* betag = (const float*)d_in[4];
    const float* lw    = (const float*)d_in[5];
    const float* beta2 = (const float*)d_in[6];
    const float* w2    = (const float*)d_in[7];
    float* out = (float*)d_out;

    char* ws = (char*)d_ws;
    float* outp_pre = (float*)(ws);                     // 256*256*361*4 = 94,633,984 B
    float* psum     = (float*)(ws + 94633984);          // 256*256*3*4   =    786,432 B
    float* pmax     = (float*)(ws + 95420416);          // 256*256*3*4   =    786,432 B
    float* g_out    = (float*)(ws + 96206848);          // 256*256*4     =    262,144 B

    hipLaunchKernelGGL(k1_conv1, dim3(3, 4, BATCH), dim3(256), 0, stream,
                       x, mask, w1p, w1g, betag, outp_pre, psum, pmax);
    hipLaunchKernelGGL(k2_pool_linear, dim3(BATCH), dim3(256), 0, stream,
                       mask, psum, pmax, lw, g_out);
    hipLaunchKernelGGL(k3_final, dim3(6, BATCH), dim3(256), 0, stream,
                       outp_pre, mask, g_out, beta2, w2, out);
    (void)in_sizes; (void)n_in; (void)out_size; (void)ws_size;
}

// Round 2
// 823.131 us; speedup vs baseline: 1.0491x; 1.0491x over previous
//
#include <hip/hip_runtime.h>
#include <math.h>

#define BATCH 256
#define CIN   512
#define CP    256
#define HW    361
#define NOUT  6

typedef short bf16x8 __attribute__((ext_vector_type(8)));
typedef float f32x4  __attribute__((ext_vector_type(4)));

__device__ __forceinline__ short f2bf(float f) {
    unsigned u = __float_as_uint(f);
    u += 0x7fffu + ((u >> 16) & 1u);
    return (short)(u >> 16);
}
__device__ __forceinline__ float bf2f(short s) {
    return __uint_as_float(((unsigned)(unsigned short)s) << 16);
}
__device__ __forceinline__ float mish_f(float v) {
    float sp = (v > 20.f) ? v : log1pf(expf(v));
    return v * tanhf(sp);
}
__device__ __forceinline__ void gl_lds16(const void* g, void* l) {
    __builtin_amdgcn_global_load_lds(
        (const __attribute__((address_space(1))) void*)g,
        (__attribute__((address_space(3))) void*)l, 16, 0, 0);
}

// ---------------------------------------------------------------------------
// K0a: weights f32 -> bf16, tiled + pre-swizzled [m(4)][kb(16)][row(128)][slot(4)*16B]
// rows 0-255 = w1p, 256-511 = w1g. Dest slot s holds source chunk s ^ ((row>>1)&3).
// ---------------------------------------------------------------------------
__global__ __launch_bounds__(256) void k0_weights(
    const float* __restrict__ w1p, const float* __restrict__ w1g,
    short* __restrict__ wT)
{
    int t = threadIdx.x;
    int r = blockIdx.x * 4 + (t >> 6);     // 0..511
    int cs = t & 63;                       // chunk-in-row: 64 x 8c
    int g = cs >> 2, s = cs & 3;           // kb group, dest slot
    int sc = s ^ ((r >> 1) & 3);           // source chunk
    const float* src = (r < 256) ? (w1p + (size_t)r * CIN)
                                 : (w1g + (size_t)(r - 256) * CIN);
    int c = g * 32 + sc * 8;
    float f[8];
    *(float4*)(f)     = *(const float4*)(src + c);
    *(float4*)(f + 4) = *(const float4*)(src + c + 4);
    bf16x8 v;
    #pragma unroll
    for (int i = 0; i < 8; ++i) v[i] = f2bf(f[i]);
    int m = r >> 7, rloc = r & 127;
    *(bf16x8*)((char*)wT + ((size_t)(m * 16 + g) * 128 + rloc) * 64 + s * 16) = v;
}

// ---------------------------------------------------------------------------
// K0b: x f32 [b][c][hw] -> bf16 tiled + pre-swizzled [b*3+n][kb(16)][row(128)][slot(4)*16B]
// rows beyond HW are zero-filled (read by GEMM, results discarded).
// ---------------------------------------------------------------------------
__global__ __launch_bounds__(256) void k0_xpose(
    const float* __restrict__ x, short* __restrict__ xT)
{
    int n = blockIdx.x, b = blockIdx.y;
    int t = threadIdx.x;
    int hw0 = n * 128;
    __shared__ float Ls[32][129];
    char* dstb = (char*)xT + (size_t)(b * 3 + n) * 16 * 8192;
    for (int kb = 0; kb < 16; ++kb) {
        int c0 = kb * 32;
        #pragma unroll
        for (int it = 0; it < 16; ++it) {
            int e = it * 256 + t;
            int c = e >> 7, hw = e & 127;
            int hwg = hw0 + hw;
            Ls[c][hw] = (hwg < HW) ? x[((size_t)b * CIN + c0 + c) * HW + hwg] : 0.f;
        }
        __syncthreads();
        #pragma unroll
        for (int pass = 0; pass < 2; ++pass) {
            int row = (t >> 2) + pass * 64;
            int s = t & 3;
            int sc = s ^ ((row >> 1) & 3);
            bf16x8 v;
            #pragma unroll
            for (int i = 0; i < 8; ++i) v[i] = f2bf(Ls[sc * 8 + i][row]);
            *(bf16x8*)(dstb + (size_t)kb * 8192 + row * 64 + s * 16) = v;
        }
        __syncthreads();
    }
}

// ---------------------------------------------------------------------------
// K1: fused conv1p+conv1g bf16 MFMA GEMM, global_load_lds staging, swizzled LDS.
// 1D grid 3072 with bijective XCD remap; decode m fastest so the 4 m-blocks
// sharing one x-tile land on the same XCD (L2 reuse).
// ---------------------------------------------------------------------------
__global__ __launch_bounds__(256) void k1_conv1(
    const short* __restrict__ wT, const short* __restrict__ xT,
    const float* __restrict__ mask, const float* __restrict__ beta_g,
    short* __restrict__ outp_pre, float* __restrict__ psum, float* __restrict__ pmax)
{
    int orig = blockIdx.x;
    int newid = (orig & 7) * 384 + (orig >> 3);   // 3072 = 8 * 384, bijective
    int m = newid & 3;
    int nb = newid >> 2;          // b*3 + n
    int n = nb % 3;
    int b = nb / 3;

    const int tid = threadIdx.x;
    const int lane = tid & 63, wid = tid >> 6;
    const int wm = wid >> 1, wn = wid & 1;
    const int lc = lane & 15, lg = lane >> 4;
    const int hw0 = n * 128;

    __shared__ __align__(16) short As[4096];   // 8 KB: [row128][slot4*8bf16]
    __shared__ __align__(16) short Bs[4096];
    __shared__ float maskS[128], betaS[128], redS[256], redM[256];

    if (tid < 128) {
        int hwg = hw0 + tid;
        maskS[tid] = (hwg < HW) ? mask[b * HW + hwg] : 0.f;
        betaS[tid] = (m >= 2) ? beta_g[(m - 2) * 128 + tid] : 0.f;
    }

    const char* Ab = (const char*)wT + (size_t)m * 16 * 8192 + wid * 2048 + lane * 16;
    const char* Bb = (const char*)xT + (size_t)nb * 16 * 8192 + wid * 2048 + lane * 16;
    char* Al = (char*)As + wid * 2048;
    char* Bl = (char*)Bs + wid * 2048;

    f32x4 acc[4][4];
    #pragma unroll
    for (int i = 0; i < 4; ++i)
        #pragma unroll
        for (int j = 0; j < 4; ++j)
            acc[i][j] = (f32x4){0.f, 0.f, 0.f, 0.f};

    for (int kb = 0; kb < 16; ++kb) {
        const char* ga = Ab + kb * 8192;
        const char* gb = Bb + kb * 8192;
        gl_lds16(ga,        Al);
        gl_lds16(ga + 1024, Al + 1024);
        gl_lds16(gb,        Bl);
        gl_lds16(gb + 1024, Bl + 1024);
        __syncthreads();

        bf16x8 aF[4], bF[4];
        #pragma unroll
        for (int mf = 0; mf < 4; ++mf) {
            int r = wm * 64 + mf * 16 + lc;
            aF[mf] = *(const bf16x8*)((const char*)As + r * 64 + ((lg ^ ((r >> 1) & 3)) * 16));
        }
        #pragma unroll
        for (int nf = 0; nf < 4; ++nf) {
            int r = wn * 64 + nf * 16 + lc;
            bF[nf] = *(const bf16x8*)((const char*)Bs + r * 64 + ((lg ^ ((r >> 1) & 3)) * 16));
        }
        #pragma unroll
        for (int mf = 0; mf < 4; ++mf)
            #pragma unroll
            for (int nf = 0; nf < 4; ++nf)
                acc[mf][nf] = __builtin_amdgcn_mfma_f32_16x16x32_bf16(
                    aF[mf], bF[nf], acc[mf][nf], 0, 0, 0);
        __syncthreads();
    }

    if (m < 2) {
        // p-branch: store pre-activation conv1p output (bf16)
        #pragma unroll
        for (int mf = 0; mf < 4; ++mf) {
            int ch = m * 128 + wm * 64 + mf * 16 + lg * 4;
            #pragma unroll
            for (int nf = 0; nf < 4; ++nf) {
                int hw = hw0 + wn * 64 + nf * 16 + lc;
                if (hw < HW) {
                    #pragma unroll
                    for (int j = 0; j < 4; ++j)
                        outp_pre[((size_t)(b * CP + ch + j)) * HW + hw] = f2bf(acc[mf][nf][j]);
                }
            }
        }
    } else {
        // g-branch: mish((acc+beta)*mask); per-channel sum & max partials
        #pragma unroll
        for (int mf = 0; mf < 4; ++mf) {
            #pragma unroll
            for (int j = 0; j < 4; ++j) {
                int rloc = wm * 64 + mf * 16 + lg * 4 + j;
                float beta = betaS[rloc];
                float s = 0.f, mx = -INFINITY;
                #pragma unroll
                for (int nf = 0; nf < 4; ++nf) {
                    int cl = wn * 64 + nf * 16 + lc;
                    int hw = hw0 + cl;
                    float mv = maskS[cl];
                    float val = mish_f((acc[mf][nf][j] + beta) * mv);
                    if (hw < HW) {
                        s += val * mv;
                        mx = fmaxf(mx, val + mv - 1.f);
                    }
                }
                #pragma unroll
                for (int off = 1; off < 16; off <<= 1) {
                    s += __shfl_xor(s, off, 64);
                    mx = fmaxf(mx, __shfl_xor(mx, off, 64));
                }
                if (lc == 0) { redS[rloc * 2 + wn] = s; redM[rloc * 2 + wn] = mx; }
            }
        }
        __syncthreads();
        if (tid < 128) {
            int ch = (m - 2) * 128 + tid;
            float s = redS[tid * 2] + redS[tid * 2 + 1];
            float mx = fmaxf(redM[tid * 2], redM[tid * 2 + 1]);
            psum[((size_t)(b * CP + ch)) * 3 + n] = s;
            pmax[((size_t)(b * CP + ch)) * 3 + n] = mx;
        }
    }
}

// ---------------------------------------------------------------------------
// K2: per-batch pooled vector + linear_g. Grid 256 blocks x 256 threads.
// ---------------------------------------------------------------------------
__global__ __launch_bounds__(256) void k2_pool_linear(
    const float* __restrict__ mask, const float* __restrict__ psum,
    const float* __restrict__ pmax, const float* __restrict__ lw,
    float* __restrict__ g_out)
{
    int b = blockIdx.x, t = threadIdx.x;
    __shared__ float pooled[768];
    __shared__ float msr[4];

    float s = 0.f;
    for (int i = t; i < HW; i += 256) s += mask[b * HW + i];
    #pragma unroll
    for (int off = 1; off < 64; off <<= 1) s += __shfl_xor(s, off, 64);
    if ((t & 63) == 0) msr[t >> 6] = s;
    __syncthreads();
    float msum = msr[0] + msr[1] + msr[2] + msr[3];

    {
        int c = t;
        const float* ps = psum + (size_t)(b * CP + c) * 3;
        const float* pm = pmax + (size_t)(b * CP + c) * 3;
        float s3 = ps[0] + ps[1] + ps[2];
        float m3 = fmaxf(fmaxf(pm[0], pm[1]), pm[2]);
        float mean = s3 / msum;
        float sq = (sqrtf(msum) - 14.f) * 0.1f;
        pooled[c] = mean; pooled[256 + c] = mean * sq; pooled[512 + c] = m3;
    }
    __syncthreads();
    {
        int o = t;
        const float* wrow = lw + (size_t)o * 768;
        float acc = 0.f;
        #pragma unroll 4
        for (int j = 0; j < 768; ++j) acc += pooled[j] * wrow[j];
        g_out[b * CP + o] = acc;
    }
}

// ---------------------------------------------------------------------------
// K3: final fused mish((outp_pre+g+beta2)*mask) -> conv2p -> mask bias.
// outp_pre is bf16 now. Grid (6 hw-tiles, 256 b) x 256 threads.
// ---------------------------------------------------------------------------
__global__ __launch_bounds__(256) void k3_final(
    const short* __restrict__ outp_pre, const float* __restrict__ mask,
    const float* __restrict__ g_out, const float* __restrict__ beta2,
    const float* __restrict__ w2, float* __restrict__ out)
{
    int ht = blockIdx.x, b = blockIdx.y;
    int t = threadIdx.x;
    __shared__ float w2S[NOUT * 256];
    __shared__ float gbS[256];
    __shared__ float part[NOUT][256];

    for (int i = t; i < NOUT * 256; i += 256) w2S[i] = w2[i];
    gbS[t] = g_out[b * CP + t] + beta2[t];
    __syncthreads();

    int hw = t & 63, cg = t >> 6;
    int hwg = ht * 64 + hw;
    bool valid = hwg < HW;
    float maskv = valid ? mask[b * HW + hwg] : 0.f;

    float acc[NOUT] = {0.f, 0.f, 0.f, 0.f, 0.f, 0.f};
    const short* src = outp_pre + ((size_t)(b * CP + cg * 64)) * HW + hwg;
    #pragma unroll 4
    for (int ci = 0; ci < 64; ++ci) {
        float v = valid ? bf2f(src[(size_t)ci * HW]) : 0.f;
        float mm = mish_f((v + gbS[cg * 64 + ci]) * maskv);
        #pragma unroll
        for (int o = 0; o < NOUT; ++o) acc[o] += mm * w2S[o * 256 + cg * 64 + ci];
    }
    #pragma unroll
    for (int o = 0; o < NOUT; ++o) part[o][t] = acc[o];
    __syncthreads();

    for (int idx = t; idx < NOUT * 64; idx += 256) {
        int o = idx >> 6, h2 = idx & 63;
        int hg = ht * 64 + h2;
        if (hg < HW) {
            float mv = mask[b * HW + hg];
            float sum = part[o][h2] + part[o][64 + h2] + part[o][128 + h2] + part[o][192 + h2];
            out[((size_t)(b * NOUT + o)) * HW + hg] = sum - (1.f - mv) * 5000.f;
        }
    }
}

extern "C" void kernel_launch(void* const* d_in, const int* in_sizes, int n_in,
                              void* d_out, int out_size, void* d_ws, size_t ws_size,
                              hipStream_t stream) {
    const float* x     = (const float*)d_in[0];
    const float* mask  = (const float*)d_in[1];
    const float* w1p   = (const float*)d_in[2];
    const float* w1g   = (const float*)d_in[3];
    const float* betag = (const float*)d_in[4];
    const float* lw    = (const float*)d_in[5];
    const float* beta2 = (const float*)d_in[6];
    const float* w2    = (const float*)d_in[7];
    float* out = (float*)d_out;

    char* ws = (char*)d_ws;
    short* outp_pre = (short*)(ws);                      // 256*256*361*2 = 47,316,992 B
    short* xT       = (short*)(ws + 47316992);           // 768*16*8192   = 100,663,296 B
    short* wT       = (short*)(ws + 147980288);          // 64*8192       =     524,288 B
    float* psum     = (float*)(ws + 148504576);          // 256*256*3*4   =     786,432 B
    float* pmax     = (float*)(ws + 149291008);          // 256*256*3*4   =     786,432 B
    float* g_out    = (float*)(ws + 150077440);          // 256*256*4     =     262,144 B

    hipLaunchKernelGGL(k0_weights, dim3(128), dim3(256), 0, stream, w1p, w1g, wT);
    hipLaunchKernelGGL(k0_xpose, dim3(3, BATCH), dim3(256), 0, stream, x, xT);
    hipLaunchKernelGGL(k1_conv1, dim3(3072), dim3(256), 0, stream,
                       wT, xT, mask, betag, outp_pre, psum, pmax);
    hipLaunchKernelGGL(k2_pool_linear, dim3(BATCH), dim3(256), 0, stream,
                       mask, psum, pmax, lw, g_out);
    hipLaunchKernelGGL(k3_final, dim3(6, BATCH), dim3(256), 0, stream,
                       outp_pre, mask, g_out, beta2, w2, out);
    (void)in_sizes; (void)n_in; (void)out_size; (void)ws_size;
}

// Round 3
// 294.057 us; speedup vs baseline: 2.9366x; 2.7992x over previous
//
#include <hip/hip_runtime.h>
#include <math.h>

#define BATCH 256
#define CIN   512
#define CP    256
#define HW    361
#define NOUT  6

typedef short bf16x8 __attribute__((ext_vector_type(8)));
typedef float f32x4  __attribute__((ext_vector_type(4)));

__device__ __forceinline__ short f2bf(float f) {
    unsigned u = __float_as_uint(f);
    u += 0x7fffu + ((u >> 16) & 1u);
    return (short)(u >> 16);
}
__device__ __forceinline__ float bf2f(short s) {
    return __uint_as_float(((unsigned)(unsigned short)s) << 16);
}
// fast mish: mish(x) = x*(w-1)/(w+1), w=(1+e^x)^2.  Guard x>30 -> x (w overflow).
__device__ __forceinline__ float mish_f(float v) {
    float u = __expf(v);
    float a = 1.f + u;
    float w = a * a;
    float r = v * (w - 1.f) * __builtin_amdgcn_rcpf(w + 1.f);
    return (v > 30.f) ? v : r;
}
__device__ __forceinline__ void gl_lds16(const void* g, void* l) {
    __builtin_amdgcn_global_load_lds(
        (const __attribute__((address_space(1))) void*)g,
        (__attribute__((address_space(3))) void*)l, 16, 0, 0);
}

// ---------------------------------------------------------------------------
// K0a: weights f32 -> bf16, tiled + pre-swizzled [m(4)][kb(16)][row(128)][slot(4)*16B]
// rows 0-255 = w1p, 256-511 = w1g. Dest slot s holds source chunk s ^ ((row>>1)&3).
// ---------------------------------------------------------------------------
__global__ __launch_bounds__(256) void k0_weights(
    const float* __restrict__ w1p, const float* __restrict__ w1g,
    short* __restrict__ wT)
{
    int t = threadIdx.x;
    int r = blockIdx.x * 4 + (t >> 6);     // 0..511
    int cs = t & 63;                       // chunk-in-row: 64 x 8c
    int g = cs >> 2, s = cs & 3;           // kb group, dest slot
    int sc = s ^ ((r >> 1) & 3);           // source chunk
    const float* src = (r < 256) ? (w1p + (size_t)r * CIN)
                                 : (w1g + (size_t)(r - 256) * CIN);
    int c = g * 32 + sc * 8;
    float f[8];
    *(float4*)(f)     = *(const float4*)(src + c);
    *(float4*)(f + 4) = *(const float4*)(src + c + 4);
    bf16x8 v;
    #pragma unroll
    for (int i = 0; i < 8; ++i) v[i] = f2bf(f[i]);
    int m = r >> 7, rloc = r & 127;
    *(bf16x8*)((char*)wT + ((size_t)(m * 16 + g) * 128 + rloc) * 64 + s * 16) = v;
}

// ---------------------------------------------------------------------------
// K0b: x f32 [b][c][hw] -> bf16 tiled + pre-swizzled [b*3+n][kb(16)][row(128)][slot4*16B]
// float4 global loads; rows beyond HW zero-filled.
// ---------------------------------------------------------------------------
__global__ __launch_bounds__(256) void k0_xpose(
    const float* __restrict__ x, short* __restrict__ xT)
{
    int n = blockIdx.x, b = blockIdx.y;
    int t = threadIdx.x;
    int hw0 = n * 128;
    __shared__ float Ls[32][132];
    char* dstb = (char*)xT + (size_t)(b * 3 + n) * 131072;
    for (int kb = 0; kb < 16; ++kb) {
        int c0 = kb * 32;
        #pragma unroll
        for (int l = 0; l < 4; ++l) {
            int idx = l * 256 + t;
            int c = idx >> 5;              // 0..31
            int hwc = (idx & 31) * 4;      // 0..124
            int hwg = hw0 + hwc;
            const float* src = x + ((size_t)b * CIN + c0 + c) * HW + hwg;
            float4 v;
            if (hwg + 3 < HW) {
                v = *(const float4*)src;
            } else {
                v.x = (hwg     < HW) ? src[0] : 0.f;
                v.y = (hwg + 1 < HW) ? src[1] : 0.f;
                v.z = (hwg + 2 < HW) ? src[2] : 0.f;
                v.w = (hwg + 3 < HW) ? src[3] : 0.f;
            }
            *(float4*)&Ls[c][hwc] = v;
        }
        __syncthreads();
        #pragma unroll
        for (int pass = 0; pass < 2; ++pass) {
            int row = (t >> 2) + pass * 64;
            int s = t & 3;
            int sc = s ^ ((row >> 1) & 3);
            bf16x8 v;
            #pragma unroll
            for (int i = 0; i < 8; ++i) v[i] = f2bf(Ls[sc * 8 + i][row]);
            *(bf16x8*)(dstb + (size_t)kb * 8192 + row * 64 + s * 16) = v;
        }
        __syncthreads();
    }
}

// ---------------------------------------------------------------------------
// K1: fused conv1p+conv1g bf16 MFMA GEMM.
// BK=128 (4 kb-units per phase), double-buffered LDS (2 x 64KB), counted vmcnt
// prefetch (depth 1), raw s_barrier (no full drains in the main loop).
// Grid 3072, XCD-bijective remap, m fastest (4 m-blocks share one xT tile).
// ---------------------------------------------------------------------------
#define STAGE(h, p)                                                        \
    do {                                                                   \
        const char* ga_ = Ab + (p) * 32768;                                \
        const char* gb_ = Bb + (p) * 32768;                                \
        char* al_ = (char*)(&As[(h)][0]) + wid * 2048;                     \
        char* bl_ = (char*)(&Bs[(h)][0]) + wid * 2048;                     \
        _Pragma("unroll")                                                  \
        for (int q_ = 0; q_ < 4; ++q_) {                                   \
            gl_lds16(ga_ + q_ * 8192,        al_ + q_ * 8192);             \
            gl_lds16(ga_ + q_ * 8192 + 1024, al_ + q_ * 8192 + 1024);      \
            gl_lds16(gb_ + q_ * 8192,        bl_ + q_ * 8192);             \
            gl_lds16(gb_ + q_ * 8192 + 1024, bl_ + q_ * 8192 + 1024);      \
        }                                                                  \
    } while (0)

__global__ __launch_bounds__(256, 1) void k1_conv1(
    const short* __restrict__ wT, const short* __restrict__ xT,
    const float* __restrict__ mask, const float* __restrict__ beta_g,
    short* __restrict__ outp_pre, float* __restrict__ psum, float* __restrict__ pmax)
{
    int orig = blockIdx.x;
    int newid = (orig & 7) * 384 + (orig >> 3);   // 3072 = 8 * 384, bijective
    int m = newid & 3;
    int nb = newid >> 2;          // b*3 + n
    int n = nb % 3;
    int b = nb / 3;

    const int tid = threadIdx.x;
    const int lane = tid & 63, wid = tid >> 6;
    const int wm = wid >> 1, wn = wid & 1;
    const int lc = lane & 15, lg = lane >> 4;
    const int hw0 = n * 128;

    __shared__ __align__(16) short As[2][16384];   // 2 x 32KB
    __shared__ __align__(16) short Bs[2][16384];
    __shared__ float maskS[128], betaS[128];
    // epilogue scratch overlays As (dead after main loop)
    float* redS = (float*)(&As[0][0]);
    float* redM = redS + 256;

    if (tid < 128) {
        int hwg = hw0 + tid;
        maskS[tid] = (hwg < HW) ? mask[b * HW + hwg] : 0.f;
        betaS[tid] = (m >= 2) ? beta_g[(m - 2) * 128 + tid] : 0.f;
    }
    // drain everything so counted vmcnt below starts from 0 outstanding
    asm volatile("s_waitcnt vmcnt(0) lgkmcnt(0)" ::: "memory");
    __builtin_amdgcn_sched_barrier(0);

    const char* Ab = (const char*)wT + (size_t)m * 131072 + wid * 2048 + lane * 16;
    const char* Bb = (const char*)xT + (size_t)nb * 131072 + wid * 2048 + lane * 16;

    f32x4 acc[4][4];
    #pragma unroll
    for (int i = 0; i < 4; ++i)
        #pragma unroll
        for (int j = 0; j < 4; ++j)
            acc[i][j] = (f32x4){0.f, 0.f, 0.f, 0.f};

    STAGE(0, 0);
    STAGE(1, 1);
    asm volatile("s_waitcnt vmcnt(16)" ::: "memory");   // buf0's 16 done
    __builtin_amdgcn_sched_barrier(0);
    __builtin_amdgcn_s_barrier();

    #pragma unroll
    for (int p = 0; p < 4; ++p) {
        const int h = p & 1;
        const char* ab = (const char*)(&As[h][0]);
        const char* bb = (const char*)(&Bs[h][0]);
        #pragma unroll
        for (int q = 0; q < 4; ++q) {
            bf16x8 aF[4], bF[4];
            #pragma unroll
            for (int mf = 0; mf < 4; ++mf) {
                int r = wm * 64 + mf * 16 + lc;
                aF[mf] = *(const bf16x8*)(ab + q * 8192 + r * 64 + ((lg ^ ((r >> 1) & 3)) * 16));
            }
            #pragma unroll
            for (int nf = 0; nf < 4; ++nf) {
                int r = wn * 64 + nf * 16 + lc;
                bF[nf] = *(const bf16x8*)(bb + q * 8192 + r * 64 + ((lg ^ ((r >> 1) & 3)) * 16));
            }
            #pragma unroll
            for (int mf = 0; mf < 4; ++mf)
                #pragma unroll
                for (int nf = 0; nf < 4; ++nf)
                    acc[mf][nf] = __builtin_amdgcn_mfma_f32_16x16x32_bf16(
                        aF[mf], bF[nf], acc[mf][nf], 0, 0, 0);
        }
        __builtin_amdgcn_s_barrier();          // all waves done reading buf h
        if (p == 0) {
            STAGE(0, 2);
            asm volatile("s_waitcnt vmcnt(16)" ::: "memory");  // buf1 ready
            __builtin_amdgcn_sched_barrier(0);
            __builtin_amdgcn_s_barrier();
        } else if (p == 1) {
            STAGE(1, 3);
            asm volatile("s_waitcnt vmcnt(16)" ::: "memory");  // buf0(p2) ready
            __builtin_amdgcn_sched_barrier(0);
            __builtin_amdgcn_s_barrier();
        } else if (p == 2) {
            asm volatile("s_waitcnt vmcnt(0)" ::: "memory");   // buf1(p3) ready
            __builtin_amdgcn_sched_barrier(0);
            __builtin_amdgcn_s_barrier();
        }
    }
    __syncthreads();   // As reuse as redS/redM below

    if (m < 2) {
        // p-branch: store pre-activation conv1p output (bf16)
        #pragma unroll
        for (int mf = 0; mf < 4; ++mf) {
            int ch = m * 128 + wm * 64 + mf * 16 + lg * 4;
            #pragma unroll
            for (int nf = 0; nf < 4; ++nf) {
                int hw = hw0 + wn * 64 + nf * 16 + lc;
                if (hw < HW) {
                    #pragma unroll
                    for (int j = 0; j < 4; ++j)
                        outp_pre[((size_t)(b * CP + ch + j)) * HW + hw] = f2bf(acc[mf][nf][j]);
                }
            }
        }
    } else {
        // g-branch: mish((acc+beta)*mask); per-channel sum & max partials
        #pragma unroll
        for (int mf = 0; mf < 4; ++mf) {
            #pragma unroll
            for (int j = 0; j < 4; ++j) {
                int rloc = wm * 64 + mf * 16 + lg * 4 + j;
                float beta = betaS[rloc];
                float s = 0.f, mx = -INFINITY;
                #pragma unroll
                for (int nf = 0; nf < 4; ++nf) {
                    int cl = wn * 64 + nf * 16 + lc;
                    int hw = hw0 + cl;
                    float mv = maskS[cl];
                    float val = mish_f((acc[mf][nf][j] + beta) * mv);
                    if (hw < HW) {
                        s += val * mv;
                        mx = fmaxf(mx, val + mv - 1.f);
                    }
                }
                #pragma unroll
                for (int off = 1; off < 16; off <<= 1) {
                    s += __shfl_xor(s, off, 64);
                    mx = fmaxf(mx, __shfl_xor(mx, off, 64));
                }
                if (lc == 0) { redS[rloc * 2 + wn] = s; redM[rloc * 2 + wn] = mx; }
            }
        }
        __syncthreads();
        if (tid < 128) {
            int ch = (m - 2) * 128 + tid;
            float s = redS[tid * 2] + redS[tid * 2 + 1];
            float mx = fmaxf(redM[tid * 2], redM[tid * 2 + 1]);
            psum[((size_t)(b * CP + ch)) * 3 + n] = s;
            pmax[((size_t)(b * CP + ch)) * 3 + n] = mx;
        }
    }
}

// ---------------------------------------------------------------------------
// K2: per-batch pooled vector + linear_g. Grid 256 blocks x 256 threads.
// ---------------------------------------------------------------------------
__global__ __launch_bounds__(256) void k2_pool_linear(
    const float* __restrict__ mask, const float* __restrict__ psum,
    const float* __restrict__ pmax, const float* __restrict__ lw,
    float* __restrict__ g_out)
{
    int b = blockIdx.x, t = threadIdx.x;
    __shared__ float pooled[768];
    __shared__ float msr[4];

    float s = 0.f;
    for (int i = t; i < HW; i += 256) s += mask[b * HW + i];
    #pragma unroll
    for (int off = 1; off < 64; off <<= 1) s += __shfl_xor(s, off, 64);
    if ((t & 63) == 0) msr[t >> 6] = s;
    __syncthreads();
    float msum = msr[0] + msr[1] + msr[2] + msr[3];

    {
        int c = t;
        const float* ps = psum + (size_t)(b * CP + c) * 3;
        const float* pm = pmax + (size_t)(b * CP + c) * 3;
        float s3 = ps[0] + ps[1] + ps[2];
        float m3 = fmaxf(fmaxf(pm[0], pm[1]), pm[2]);
        float mean = s3 / msum;
        float sq = (sqrtf(msum) - 14.f) * 0.1f;
        pooled[c] = mean; pooled[256 + c] = mean * sq; pooled[512 + c] = m3;
    }
    __syncthreads();
    {
        int o = t;
        const float* wrow = lw + (size_t)o * 768;
        float acc = 0.f;
        #pragma unroll 4
        for (int j = 0; j < 768; ++j) acc += pooled[j] * wrow[j];
        g_out[b * CP + o] = acc;
    }
}

// ---------------------------------------------------------------------------
// K3: final fused mish((outp_pre+g+beta2)*mask) -> conv2p -> mask bias.
// outp_pre is bf16. Grid (6 hw-tiles, 256 b) x 256 threads.
// ---------------------------------------------------------------------------
__global__ __launch_bounds__(256) void k3_final(
    const short* __restrict__ outp_pre, const float* __restrict__ mask,
    const float* __restrict__ g_out, const float* __restrict__ beta2,
    const float* __restrict__ w2, float* __restrict__ out)
{
    int ht = blockIdx.x, b = blockIdx.y;
    int t = threadIdx.x;
    __shared__ float w2S[NOUT * 256];
    __shared__ float gbS[256];
    __shared__ float part[NOUT][256];

    for (int i = t; i < NOUT * 256; i += 256) w2S[i] = w2[i];
    gbS[t] = g_out[b * CP + t] + beta2[t];
    __syncthreads();

    int hw = t & 63, cg = t >> 6;
    int hwg = ht * 64 + hw;
    bool valid = hwg < HW;
    float maskv = valid ? mask[b * HW + hwg] : 0.f;

    float acc[NOUT] = {0.f, 0.f, 0.f, 0.f, 0.f, 0.f};
    const short* src = outp_pre + ((size_t)(b * CP + cg * 64)) * HW + hwg;
    #pragma unroll 4
    for (int ci = 0; ci < 64; ++ci) {
        float v = valid ? bf2f(src[(size_t)ci * HW]) : 0.f;
        float mm = mish_f((v + gbS[cg * 64 + ci]) * maskv);
        #pragma unroll
        for (int o = 0; o < NOUT; ++o) acc[o] += mm * w2S[o * 256 + cg * 64 + ci];
    }
    #pragma unroll
    for (int o = 0; o < NOUT; ++o) part[o][t] = acc[o];
    __syncthreads();

    for (int idx = t; idx < NOUT * 64; idx += 256) {
        int o = idx >> 6, h2 = idx & 63;
        int hg = ht * 64 + h2;
        if (hg < HW) {
            float mv = mask[b * HW + hg];
            float sum = part[o][h2] + part[o][64 + h2] + part[o][128 + h2] + part[o][192 + h2];
            out[((size_t)(b * NOUT + o)) * HW + hg] = sum - (1.f - mv) * 5000.f;
        }
    }
}

extern "C" void kernel_launch(void* const* d_in, const int* in_sizes, int n_in,
                              void* d_out, int out_size, void* d_ws, size_t ws_size,
                              hipStream_t stream) {
    const float* x     = (const float*)d_in[0];
    const float* mask  = (const float*)d_in[1];
    const float* w1p   = (const float*)d_in[2];
    const float* w1g   = (const float*)d_in[3];
    const float* betag = (const float*)d_in[4];
    const float* lw    = (const float*)d_in[5];
    const float* beta2 = (const float*)d_in[6];
    const float* w2    = (const float*)d_in[7];
    float* out = (float*)d_out;

    char* ws = (char*)d_ws;
    short* outp_pre = (short*)(ws);                      // 256*256*361*2 = 47,316,992 B
    short* xT       = (short*)(ws + 47316992);           // 768*131072    = 100,663,296 B
    short* wT       = (short*)(ws + 147980288);          // 4*131072      =     524,288 B
    float* psum     = (float*)(ws + 148504576);          // 256*256*3*4   =     786,432 B
    float* pmax     = (float*)(ws + 149291008);          // 256*256*3*4   =     786,432 B
    float* g_out    = (float*)(ws + 150077440);          // 256*256*4     =     262,144 B

    hipLaunchKernelGGL(k0_weights, dim3(128), dim3(256), 0, stream, w1p, w1g, wT);
    hipLaunchKernelGGL(k0_xpose, dim3(3, BATCH), dim3(256), 0, stream, x, xT);
    hipLaunchKernelGGL(k1_conv1, dim3(3072), dim3(256), 0, stream,
                       wT, xT, mask, betag, outp_pre, psum, pmax);
    hipLaunchKernelGGL(k2_pool_linear, dim3(BATCH), dim3(256), 0, stream,
                       mask, psum, pmax, lw, g_out);
    hipLaunchKernelGGL(k3_final, dim3(6, BATCH), dim3(256), 0, stream,
                       outp_pre, mask, g_out, beta2, w2, out);
    (void)in_sizes; (void)n_in; (void)out_size; (void)ws_size;
}